// Round 6
// baseline (470.532 us; speedup 1.0000x reference)
//
#include <hip/hip_runtime.h>

#define MAXD 10
#define TSTEPS 4
#define KD 80      // IN + EC
#define IN 64
#define ECH 16
#define TILE_N 64   // nodes per block in y_kernel
#define TILE_Z 128  // edges per block in z_kernel

#define AGG_BLOCK 256
#define GEPW 8                          // edges per 16-lane group (serial)
#define AGG_EPB (AGG_BLOCK / 16 * GEPW) // 128 edges per block

__device__ __forceinline__ float sigmoidf(float v) {
    return 1.0f / (1.0f + __expf(-v));
}

// ---------------- preprocessing ----------------
// deg[] counts out-edges EXCLUDING self loop; bucket = min(deg, MAXD-1).

__global__ __launch_bounds__(256) void hist_kernel(const int* __restrict__ ei,
                                                   int* deg, int* in_cnt, int E) {
    int e = blockIdx.x * 256 + threadIdx.x;
    if (e < E) {
        atomicAdd(&deg[ei[e]], 1);
        atomicAdd(&in_cnt[ei[E + e]], 1);
    }
}

// per-bucket EDGE counts (LDS-aggregated)
__global__ __launch_bounds__(256) void eb_count_kernel(const int* __restrict__ ei,
                                                       const int* __restrict__ deg,
                                                       int* eb_cnt, int E) {
    __shared__ int h[MAXD];
    const int t = threadIdx.x;
    if (t < MAXD) h[t] = 0;
    __syncthreads();
    int e = blockIdx.x * 256 + t;
    if (e < E) {
        int dg = deg[ei[e]];
        int b = (dg < MAXD - 1) ? dg : (MAXD - 1);
        atomicAdd(&h[b], 1);
    }
    __syncthreads();
    if (t < MAXD && h[t] > 0) atomicAdd(&eb_cnt[t], h[t]);
}

// per-bucket NODE counts (LDS-aggregated)
__global__ __launch_bounds__(256) void nb_count_kernel(const int* __restrict__ deg, int* cnt, int N) {
    __shared__ int h[MAXD];
    const int t = threadIdx.x;
    if (t < MAXD) h[t] = 0;
    __syncthreads();
    int n = blockIdx.x * 256 + t;
    if (n < N) {
        int dg = deg[n];
        int b = (dg < MAXD - 1) ? dg : (MAXD - 1);
        atomicAdd(&h[b], 1);
    }
    __syncthreads();
    if (t < MAXD && h[t] > 0) atomicAdd(&cnt[t], h[t]);
}

// fused scans: in_cnt -> cursorN (per-dst CSR cursor); nb_cnt -> nb_cursor; eb_cnt -> eb_cursor
__global__ __launch_bounds__(256) void scan_kernel(const int* __restrict__ in_cnt,
                                                   int* cursor,
                                                   const int* __restrict__ nb_cnt, int* nb_cursor,
                                                   const int* __restrict__ eb_cnt, int* eb_cursor,
                                                   int N) {
    __shared__ int part[256];
    const int t = threadIdx.x;
    const int chunk = (N + 255) / 256;
    const int lo = t * chunk;
    const int hi = min(lo + chunk, N);
    int s = 0;
    for (int i = lo; i < hi; ++i) s += in_cnt[i];
    part[t] = s;
    __syncthreads();
    if (t == 0) {
        int a = 0;
        for (int i = 0; i < 256; ++i) { int v = part[i]; part[i] = a; a += v; }
        int acc = 0;
        for (int b = 0; b < MAXD; ++b) { nb_cursor[b] = acc; acc += nb_cnt[b]; }
        acc = 0;
        for (int b = 0; b < MAXD; ++b) { eb_cursor[b] = acc; acc += eb_cnt[b]; }
    }
    __syncthreads();
    int a = part[t];
    for (int i = lo; i < hi; ++i) { cursor[i] = a; a += in_cnt[i]; }
}

__global__ __launch_bounds__(256) void nb_scatter_kernel(const int* __restrict__ deg,
                                                         int* cursor, int* node_list, int N) {
    __shared__ int h[MAXD];
    __shared__ int base[MAXD];
    const int t = threadIdx.x;
    if (t < MAXD) h[t] = 0;
    __syncthreads();
    const int n = blockIdx.x * 256 + t;
    int b = 0, loc = 0;
    const bool valid = n < N;
    if (valid) {
        int dg = deg[n];
        b = (dg < MAXD - 1) ? dg : (MAXD - 1);
        loc = atomicAdd(&h[b], 1);
    }
    __syncthreads();
    if (t < MAXD) base[t] = (h[t] > 0) ? atomicAdd(&cursor[t], h[t]) : 0;
    __syncthreads();
    if (valid) node_list[base[b] + loc] = n;
}

// scatter edges: bucket-sorted arrays (ea_bkt, src_bkt, ebkt) for z-GEMM,
// plus the dst-CSR position each edge's z goes to (zpos_bkt) and dst per CSR pos.
__global__ __launch_bounds__(256) void edge_scatter_kernel(
    const int* __restrict__ ei, const float* __restrict__ ea, const int* __restrict__ deg,
    int* cursorN, int* eb_cursor,
    int* dst_csr, int* src_bkt, int* zpos_bkt, int* ebkt, float* ea_bkt, int E)
{
    __shared__ int h[MAXD];
    __shared__ int hbase[MAXD];
    const int t = threadIdx.x;
    if (t < MAXD) h[t] = 0;
    __syncthreads();

    const int e = blockIdx.x * 256 + t;
    const bool valid = e < E;
    int s = 0, d = 0, b = 0, loc = 0;
    if (valid) {
        s = ei[e]; d = ei[E + e];
        int dg = deg[s];
        b = (dg < MAXD - 1) ? dg : (MAXD - 1);
        loc = atomicAdd(&h[b], 1);
    }
    __syncthreads();
    if (t < MAXD) hbase[t] = (h[t] > 0) ? atomicAdd(&eb_cursor[t], h[t]) : 0;
    __syncthreads();

    if (valid) {
        const int posz = hbase[b] + loc;
        const int pos = atomicAdd(&cursorN[d], 1);
        dst_csr[pos] = d;
        src_bkt[posz] = s;
        zpos_bkt[posz] = pos;
        ebkt[posz] = b;
        const float4* p = (const float4*)(ea + (size_t)e * ECH);
        float4* o = (float4*)(ea_bkt + (size_t)posz * ECH);
        o[0] = p[0]; o[1] = p[1]; o[2] = p[2]; o[3] = p[3];
    }
}

// ---------------- per-timestep: node transform y = Wx[b]^T x ----------------
// Also initializes out[n] = sigmoid(y[n]) (the self-loop message).

__global__ __launch_bounds__(256) void y_kernel(
    const float* __restrict__ xin, float* __restrict__ y, float* __restrict__ out,
    const int* __restrict__ node_list, const int* __restrict__ deg,
    const float* __restrict__ Wt, int N)
{
    __shared__ float Ws[IN][IN];           // 16 KB
    __shared__ float Ms[IN][TILE_N + 4];   // 17.4 KB
    __shared__ int id_s[TILE_N];
    __shared__ int bkt_s[TILE_N];

    const int t = threadIdx.x;
    const int i0 = blockIdx.x * TILE_N;
    const int ntile = min(TILE_N, N - i0);

    {
        const int e = t >> 2;
        const bool valid = e < ntile;
        const int c0 = (t & 3) * 16;
        const float4 z4 = make_float4(0.f, 0.f, 0.f, 0.f);
        int node = valid ? node_list[i0 + e] : 0;
        const float* xp = xin + (size_t)node * IN + c0;
        #pragma unroll
        for (int i = 0; i < 16; i += 4) {
            float4 v = valid ? *(const float4*)(xp + i) : z4;
            Ms[c0 + i + 0][e] = v.x; Ms[c0 + i + 1][e] = v.y;
            Ms[c0 + i + 2][e] = v.z; Ms[c0 + i + 3][e] = v.w;
        }
        if (t < TILE_N) {
            if (t < ntile) {
                int id = node_list[i0 + t];
                id_s[t] = id;
                int dg = deg[id];
                bkt_s[t] = (dg < MAXD - 1) ? dg : (MAXD - 1);
            } else { id_s[t] = 0; bkt_s[t] = -1; }
        }
    }
    __syncthreads();

    const int b_first = bkt_s[0];
    const int b_last = bkt_s[ntile - 1];
    const int eg4 = (t >> 4) * 4;
    const int cg4 = (t & 15) * 4;

    for (int b = b_first; b <= b_last; ++b) {
        if (b != b_first) __syncthreads();
        {
            const float4* Wb = (const float4*)(Wt + (size_t)b * KD * IN);
            float4* Wsp = (float4*)Ws;
            #pragma unroll
            for (int q = 0; q < 4; ++q) Wsp[t + q * 256] = Wb[t + q * 256];
        }
        __syncthreads();

        float acc[4][4];
        #pragma unroll
        for (int e2 = 0; e2 < 4; ++e2)
            #pragma unroll
            for (int c = 0; c < 4; ++c) acc[e2][c] = 0.f;

        #pragma unroll 8
        for (int k = 0; k < IN; ++k) {
            const float4 w = *(const float4*)&Ws[k][cg4];
            const float4 m = *(const float4*)&Ms[k][eg4];
            const float me[4] = {m.x, m.y, m.z, m.w};
            #pragma unroll
            for (int e2 = 0; e2 < 4; ++e2) {
                acc[e2][0] += me[e2] * w.x;
                acc[e2][1] += me[e2] * w.y;
                acc[e2][2] += me[e2] * w.z;
                acc[e2][3] += me[e2] * w.w;
            }
        }

        #pragma unroll
        for (int e2 = 0; e2 < 4; ++e2) {
            const int el = eg4 + e2;
            if (el < ntile && bkt_s[el] == b) {
                const size_t o = (size_t)id_s[el] * IN + cg4;
                float4 v = make_float4(acc[e2][0], acc[e2][1], acc[e2][2], acc[e2][3]);
                *(float4*)(y + o) = v;
                float4 sv = make_float4(sigmoidf(v.x), sigmoidf(v.y),
                                        sigmoidf(v.z), sigmoidf(v.w));
                *(float4*)(out + o) = sv;
            }
        }
    }
}

// ---------------- per-timestep: edge transform (bucket-tiled GEMM) ----------------
// zs[zpos] = sigmoid(y[src] + We[b]^T ea)   written into dst-CSR position.

__global__ __launch_bounds__(256) void z_kernel(
    const float* __restrict__ y, float* __restrict__ zs,
    const int* __restrict__ src_bkt, const int* __restrict__ zpos_bkt,
    const int* __restrict__ ebkt, const float* __restrict__ ea_bkt,
    const float* __restrict__ Wt, int E)
{
    __shared__ float Wz[ECH][IN];           // 4 KB
    __shared__ float Ez[ECH][TILE_Z + 4];   // 8.25 KB
    __shared__ int src_s[TILE_Z];
    __shared__ int zp_s[TILE_Z];
    __shared__ int bkt_s[TILE_Z];

    const int t = threadIdx.x;
    const int i0 = blockIdx.x * TILE_Z;
    const int ntile = min(TILE_Z, E - i0);

    {
        const int e = t >> 1;
        const bool valid = e < ntile;
        const int j0 = (t & 1) * 8;
        const float4 z4 = make_float4(0.f, 0.f, 0.f, 0.f);
        const float* ep = ea_bkt + (size_t)(i0 + e) * ECH + j0;
        #pragma unroll
        for (int i = 0; i < 8; i += 4) {
            float4 v = valid ? *(const float4*)(ep + i) : z4;
            Ez[j0 + i + 0][e] = v.x; Ez[j0 + i + 1][e] = v.y;
            Ez[j0 + i + 2][e] = v.z; Ez[j0 + i + 3][e] = v.w;
        }
        if (t < TILE_Z) {
            if (t < ntile) {
                src_s[t] = src_bkt[i0 + t];
                zp_s[t] = zpos_bkt[i0 + t];
                bkt_s[t] = ebkt[i0 + t];
            } else { src_s[t] = 0; zp_s[t] = 0; bkt_s[t] = -1; }
        }
    }
    __syncthreads();

    const int b_first = bkt_s[0];
    const int b_last = bkt_s[ntile - 1];
    const int eg8 = (t >> 4) * 8;
    const int cg4 = (t & 15) * 4;

    for (int b = b_first; b <= b_last; ++b) {
        if (b != b_first) __syncthreads();
        // stage We rows (64..79) of expert b: 1024 floats
        ((float4*)Wz)[t] = ((const float4*)(Wt + (size_t)b * KD * IN + IN * IN))[t];
        __syncthreads();

        float acc[8][4];
        #pragma unroll
        for (int e2 = 0; e2 < 8; ++e2)
            #pragma unroll
            for (int c = 0; c < 4; ++c) acc[e2][c] = 0.f;

        #pragma unroll
        for (int k = 0; k < ECH; ++k) {
            const float4 w  = *(const float4*)&Wz[k][cg4];
            const float4 m0 = *(const float4*)&Ez[k][eg8];
            const float4 m1 = *(const float4*)&Ez[k][eg8 + 4];
            const float me[8] = {m0.x, m0.y, m0.z, m0.w, m1.x, m1.y, m1.z, m1.w};
            #pragma unroll
            for (int e2 = 0; e2 < 8; ++e2) {
                acc[e2][0] += me[e2] * w.x;
                acc[e2][1] += me[e2] * w.y;
                acc[e2][2] += me[e2] * w.z;
                acc[e2][3] += me[e2] * w.w;
            }
        }

        #pragma unroll
        for (int e2 = 0; e2 < 8; ++e2) {
            const int el = eg8 + e2;
            if (el < ntile && bkt_s[el] == b) {
                const float4 yv = *(const float4*)(y + (size_t)src_s[el] * IN + cg4);
                float4 r = make_float4(sigmoidf(yv.x + acc[e2][0]),
                                       sigmoidf(yv.y + acc[e2][1]),
                                       sigmoidf(yv.z + acc[e2][2]),
                                       sigmoidf(yv.w + acc[e2][3]));
                *(float4*)(zs + (size_t)zp_s[el] * IN + cg4) = r;
            }
        }
    }
}

// ---------------- per-timestep: segmented sum over dst-sorted zs ----------------
// No LDS, no gather: each 16-lane group streams GEPW consecutive edges,
// accumulates runs of equal dst in registers, flushes via atomicAdd.

__global__ __launch_bounds__(AGG_BLOCK) void agg4_kernel(
    const float* __restrict__ zs, float* __restrict__ out,
    const int* __restrict__ dst_csr, int E)
{
    const int t = threadIdx.x;
    const int lane = t & 63;
    const int grp_in_wave = (lane >> 4);   // 0..3
    const int gl = lane & 15;
    const int c0 = gl * 4;
    const int base = blockIdx.x * AGG_EPB + (t >> 4) * GEPW;
    const int cnt = min(GEPW, E - base);
    if (cnt <= 0) return;

    // lane gl holds dst of edge base + (gl & 7)
    int d_r = -1;
    {
        int m_idx = base + (gl & (GEPW - 1));
        if (m_idx < E) d_r = dst_csr[m_idx];
    }
    const int lane0 = grp_in_wave * 16;

    // load all GEPW z-vectors up front (independent)
    float4 zv[GEPW];
    #pragma unroll
    for (int i = 0; i < GEPW; ++i) {
        zv[i] = (i < cnt) ? *(const float4*)(zs + (size_t)(base + i) * IN + c0)
                          : make_float4(0.f, 0.f, 0.f, 0.f);
    }

    int cur_d = __shfl(d_r, lane0);
    float4 acc = make_float4(0.f, 0.f, 0.f, 0.f);
    #pragma unroll
    for (int i = 0; i < GEPW; ++i) {
        if (i < cnt) {
            const int d = __shfl(d_r, lane0 + i);
            if (d != cur_d) {
                float* op = out + (size_t)cur_d * IN + c0;
                atomicAdd(op + 0, acc.x); atomicAdd(op + 1, acc.y);
                atomicAdd(op + 2, acc.z); atomicAdd(op + 3, acc.w);
                acc = make_float4(0.f, 0.f, 0.f, 0.f);
                cur_d = d;
            }
            acc.x += zv[i].x; acc.y += zv[i].y;
            acc.z += zv[i].z; acc.w += zv[i].w;
        }
    }
    float* op = out + (size_t)cur_d * IN + c0;
    atomicAdd(op + 0, acc.x); atomicAdd(op + 1, acc.y);
    atomicAdd(op + 2, acc.z); atomicAdd(op + 3, acc.w);
}

// ---------------- readout + pooling ----------------

__global__ __launch_bounds__(256) void readout_kernel(
    const float* __restrict__ x, const float* __restrict__ Wr,
    const int* __restrict__ batch, float* __restrict__ pooled, int N)
{
    __shared__ float Wr_s[TSTEPS][10][IN];
    __shared__ float pool_s[64 * 10];
    const int t = threadIdx.x;
    for (int idx = t; idx < TSTEPS * IN * 10; idx += 256) {
        int tt = idx / (IN * 10);
        int r = idx % (IN * 10);
        int k = r / 10;
        int j = r % 10;
        Wr_s[tt][j][k] = Wr[idx];
    }
    for (int idx = t; idx < 64 * 10; idx += 256) pool_s[idx] = 0.f;
    __syncthreads();

    const int n = blockIdx.x * 256 + t;
    if (n < N) {
        float xr[IN];
        const float4* xp = (const float4*)(x + (size_t)n * IN);
        #pragma unroll
        for (int i = 0; i < IN / 4; ++i) ((float4*)xr)[i] = xp[i];
        float out10[10];
        #pragma unroll
        for (int j = 0; j < 10; ++j) out10[j] = 0.f;
        for (int tt = 0; tt < TSTEPS; ++tt) {
            float lg[10];
            #pragma unroll
            for (int j = 0; j < 10; ++j) {
                const float4* wp = (const float4*)Wr_s[tt][j];
                float s = 0.f;
                #pragma unroll
                for (int i = 0; i < IN / 4; ++i) {
                    float4 w = wp[i];
                    float4 xv = ((const float4*)xr)[i];
                    s += w.x * xv.x + w.y * xv.y + w.z * xv.z + w.w * xv.w;
                }
                lg[j] = s;
            }
            float mx = lg[0];
            #pragma unroll
            for (int j = 1; j < 10; ++j) mx = fmaxf(mx, lg[j]);
            float sum = 0.f;
            #pragma unroll
            for (int j = 0; j < 10; ++j) { lg[j] = __expf(lg[j] - mx); sum += lg[j]; }
            float inv = 1.f / sum;
            #pragma unroll
            for (int j = 0; j < 10; ++j) out10[j] += lg[j] * inv;
        }
        const int g = batch[n];
        #pragma unroll
        for (int j = 0; j < 10; ++j) atomicAdd(&pool_s[g * 10 + j], out10[j]);
    }
    __syncthreads();
    for (int idx = t; idx < 64 * 10; idx += 256) {
        float v = pool_s[idx];
        if (v != 0.f) atomicAdd(&pooled[idx], v);
    }
}

// ---------------- final MLP ----------------

__global__ __launch_bounds__(256) void mlp_kernel(
    const float* __restrict__ pooled,
    const float* __restrict__ fc1w, const float* __restrict__ fc1b,
    const float* __restrict__ fc2w, const float* __restrict__ fc2b,
    const float* __restrict__ fc3w, const float* __restrict__ fc3b,
    float* __restrict__ out, int G)
{
    __shared__ float p_s[64 * 10];
    __shared__ float h1[64 * 128];
    __shared__ float h2[64 * 64];
    const int t = threadIdx.x;
    for (int idx = t; idx < G * 10; idx += 256) p_s[idx] = pooled[idx];
    __syncthreads();
    for (int idx = t; idx < G * 128; idx += 256) {
        int g = idx >> 7, j = idx & 127;
        float s = fc1b[j];
        #pragma unroll
        for (int k = 0; k < 10; ++k) s += p_s[g * 10 + k] * fc1w[k * 128 + j];
        h1[idx] = (s > 0.f) ? s : 0.01f * s;
    }
    __syncthreads();
    for (int idx = t; idx < G * 64; idx += 256) {
        int g = idx >> 6, j = idx & 63;
        float s = fc2b[j];
        for (int k = 0; k < 128; ++k) s += h1[(g << 7) + k] * fc2w[(k << 6) + j];
        h2[idx] = (s > 0.f) ? s : 0.01f * s;
    }
    __syncthreads();
    if (t < G) {
        float s = fc3b[0];
        for (int k = 0; k < 64; ++k) s += h2[(t << 6) + k] * fc3w[k];
        out[t] = (s > 0.f) ? s : 0.01f * s;
    }
}

// ---------------- launch ----------------

extern "C" void kernel_launch(void* const* d_in, const int* in_sizes, int n_in,
                              void* d_out, int out_size, void* d_ws, size_t ws_size,
                              hipStream_t stream)
{
    const float* x     = (const float*)d_in[0];
    const float* ea    = (const float*)d_in[1];
    const float* Wmsg  = (const float*)d_in[2];
    const float* Wread = (const float*)d_in[3];
    const float* fc1w  = (const float*)d_in[4];
    const float* fc1b  = (const float*)d_in[5];
    const float* fc2w  = (const float*)d_in[6];
    const float* fc2b  = (const float*)d_in[7];
    const float* fc3w  = (const float*)d_in[8];
    const float* fc3b  = (const float*)d_in[9];
    const int* ei      = (const int*)d_in[10];
    const int* batch   = (const int*)d_in[11];

    const int N = in_sizes[0] / IN;
    const int E = in_sizes[10] / 2;

    char* ws = (char*)d_ws;
    size_t off = 0;
    auto take = [&](size_t bytes) {
        char* p = ws + off;
        off = (off + bytes + 255) & ~(size_t)255;
        return p;
    };
    // zero-region: [meta | pooled | deg | in_cnt] — single memset per launch
    int* meta      = (int*)take(256);   // [0..9]=nb_cnt [16..25]=nb_cur [32..41]=eb_cnt [48..57]=eb_cur
    float* pooled  = (float*)take(64 * 10 * 4);
    int* deg       = (int*)take((size_t)N * 4);
    int* in_cnt    = (int*)take((size_t)N * 4);
    const size_t zero_bytes = (size_t)((char*)in_cnt - (char*)meta) + (size_t)N * 4;
    int* node_list = (int*)take((size_t)N * 4);
    int* cursorN   = (int*)take((size_t)N * 4);
    int* dst_csr   = (int*)take((size_t)E * 4);
    int* src_bkt   = (int*)take((size_t)E * 4);
    int* zpos_bkt  = (int*)take((size_t)E * 4);
    int* ebkt      = (int*)take((size_t)E * 4);
    float* ea_bkt  = (float*)take((size_t)E * ECH * 4);
    float* zs      = (float*)take((size_t)E * IN * 4);
    float* ybuf    = (float*)take((size_t)N * IN * 4);
    float* xbA     = (float*)take((size_t)N * IN * 4);
    float* xbB     = (float*)take((size_t)N * IN * 4);

    int* nb_cnt = meta;
    int* nb_cursor = meta + 16;
    int* eb_cnt = meta + 32;
    int* eb_cursor = meta + 48;

    const int nbN = (N + 255) / 256;
    const int nbE = (E + 255) / 256;

    hipMemsetAsync(meta, 0, zero_bytes, stream);
    hist_kernel<<<nbE, 256, 0, stream>>>(ei, deg, in_cnt, E);
    eb_count_kernel<<<nbE, 256, 0, stream>>>(ei, deg, eb_cnt, E);
    nb_count_kernel<<<nbN, 256, 0, stream>>>(deg, nb_cnt, N);
    scan_kernel<<<1, 256, 0, stream>>>(in_cnt, cursorN, nb_cnt, nb_cursor,
                                       eb_cnt, eb_cursor, N);
    nb_scatter_kernel<<<nbN, 256, 0, stream>>>(deg, nb_cursor, node_list, N);
    edge_scatter_kernel<<<nbE, 256, 0, stream>>>(ei, ea, deg, cursorN, eb_cursor,
                                                 dst_csr, src_bkt, zpos_bkt, ebkt, ea_bkt, E);

    const int nblkY = (N + TILE_N - 1) / TILE_N;
    const int nblkZ = (E + TILE_Z - 1) / TILE_Z;
    const int nblkA = (E + AGG_EPB - 1) / AGG_EPB;
    const float* xi = x;
    float* bufs[2] = {xbA, xbB};
    for (int tt = 0; tt < TSTEPS; ++tt) {
        const float* Wt = Wmsg + (size_t)tt * MAXD * KD * IN;
        float* xo = bufs[tt & 1];
        y_kernel<<<nblkY, 256, 0, stream>>>(xi, ybuf, xo, node_list, deg, Wt, N);
        z_kernel<<<nblkZ, 256, 0, stream>>>(ybuf, zs, src_bkt, zpos_bkt, ebkt,
                                            ea_bkt, Wt, E);
        agg4_kernel<<<nblkA, AGG_BLOCK, 0, stream>>>(zs, xo, dst_csr, E);
        xi = xo;
    }

    readout_kernel<<<nbN, 256, 0, stream>>>(xi, Wread, batch, pooled, N);
    mlp_kernel<<<1, 256, 0, stream>>>(pooled, fc1w, fc1b, fc2w, fc2b, fc3w, fc3b,
                                      (float*)d_out, out_size);
}

// Round 7
// 448.994 us; speedup vs baseline: 1.0480x; 1.0480x over previous
//
#include <hip/hip_runtime.h>

#define MAXD 10
#define TSTEPS 4
#define KD 80      // IN + EC
#define IN 64
#define ECH 16
#define TILE_N 64  // nodes per block in y_kernel

#define AGG_BLOCK 512
#define GEPW 4                          // edges per 16-lane group (serial)
#define AGG_EPB (AGG_BLOCK / 16 * GEPW) // 128 edges per block

__device__ __forceinline__ float sigmoidf(float v) {
    return 1.0f / (1.0f + __expf(-v));
}

// ---------------- preprocessing ----------------
// deg[] counts out-edges EXCLUDING self loop; bucket = min(deg, MAXD-1).

__global__ __launch_bounds__(256) void hist_kernel(const int* __restrict__ ei,
                                                   int* deg, int* in_cnt, int E) {
    int e = blockIdx.x * 256 + threadIdx.x;
    if (e < E) {
        atomicAdd(&deg[ei[e]], 1);
        atomicAdd(&in_cnt[ei[E + e]], 1);
    }
}

// fused: exclusive scan of in_cnt -> cursorN, node-bucket histogram (from deg)
// -> nb_cursor (exclusive scan of bucket counts).
__global__ __launch_bounds__(256) void scan_kernel(const int* __restrict__ in_cnt,
                                                   int* cursor,
                                                   const int* __restrict__ deg,
                                                   int* nb_cursor, int N) {
    __shared__ int part[256];
    __shared__ int nbh[MAXD];
    const int t = threadIdx.x;
    if (t < MAXD) nbh[t] = 0;
    __syncthreads();
    const int chunk = (N + 255) / 256;
    const int lo = t * chunk;
    const int hi = min(lo + chunk, N);
    int s = 0;
    for (int i = lo; i < hi; ++i) {
        s += in_cnt[i];
        int dg = deg[i];
        int b = (dg < MAXD - 1) ? dg : (MAXD - 1);
        atomicAdd(&nbh[b], 1);
    }
    part[t] = s;
    __syncthreads();
    if (t == 0) {
        int a = 0;
        for (int i = 0; i < 256; ++i) { int v = part[i]; part[i] = a; a += v; }
        int acc = 0;
        for (int b = 0; b < MAXD; ++b) { nb_cursor[b] = acc; acc += nbh[b]; }
    }
    __syncthreads();
    int a = part[t];
    for (int i = lo; i < hi; ++i) { cursor[i] = a; a += in_cnt[i]; }
}

__global__ __launch_bounds__(256) void nb_scatter_kernel(const int* __restrict__ deg,
                                                         int* cursor, int* node_list, int N) {
    __shared__ int h[MAXD];
    __shared__ int base[MAXD];
    const int t = threadIdx.x;
    if (t < MAXD) h[t] = 0;
    __syncthreads();
    const int n = blockIdx.x * 256 + t;
    int b = 0, loc = 0;
    const bool valid = n < N;
    if (valid) {
        int dg = deg[n];
        b = (dg < MAXD - 1) ? dg : (MAXD - 1);
        loc = atomicAdd(&h[b], 1);
    }
    __syncthreads();
    if (t < MAXD) base[t] = (h[t] > 0) ? atomicAdd(&cursor[t], h[t]) : 0;
    __syncthreads();
    if (valid) node_list[base[b] + loc] = n;
}

// scatter edges into dst-CSR order (also store dst per edge)
__global__ __launch_bounds__(256) void csr_scatter_kernel(
    const int* __restrict__ ei, const float* __restrict__ ea, const int* __restrict__ deg,
    int* cursor, int* src_csr, int* dst_csr, int* bkt_csr, float* ea_csr, int E)
{
    int e = blockIdx.x * 256 + threadIdx.x;
    if (e >= E) return;
    int s = ei[e], d = ei[E + e];
    int dg = deg[s];
    int b = (dg < MAXD - 1) ? dg : (MAXD - 1);
    int pos = atomicAdd(&cursor[d], 1);
    src_csr[pos] = s;
    dst_csr[pos] = d;
    bkt_csr[pos] = b;
    const float4* p = (const float4*)(ea + (size_t)e * ECH);
    float4* o = (float4*)(ea_csr + (size_t)pos * ECH);
    o[0] = p[0]; o[1] = p[1]; o[2] = p[2]; o[3] = p[3];
}

// ---------------- per-timestep: node transform y = Wx[b]^T x ----------------
// Also initializes out[n] = sigmoid(y[n]) (the self-loop message).

__global__ __launch_bounds__(256) void y_kernel(
    const float* __restrict__ xin, float* __restrict__ y, float* __restrict__ out,
    const int* __restrict__ node_list, const int* __restrict__ deg,
    const float* __restrict__ Wt, int N)
{
    __shared__ float Ws[IN][IN];           // 16 KB
    __shared__ float Ms[IN][TILE_N + 4];   // 17.4 KB
    __shared__ int id_s[TILE_N];
    __shared__ int bkt_s[TILE_N];

    const int t = threadIdx.x;
    const int i0 = blockIdx.x * TILE_N;
    const int ntile = min(TILE_N, N - i0);

    {
        const int e = t >> 2;
        const bool valid = e < ntile;
        const int c0 = (t & 3) * 16;
        const float4 z4 = make_float4(0.f, 0.f, 0.f, 0.f);
        int node = valid ? node_list[i0 + e] : 0;
        const float* xp = xin + (size_t)node * IN + c0;
        #pragma unroll
        for (int i = 0; i < 16; i += 4) {
            float4 v = valid ? *(const float4*)(xp + i) : z4;
            Ms[c0 + i + 0][e] = v.x; Ms[c0 + i + 1][e] = v.y;
            Ms[c0 + i + 2][e] = v.z; Ms[c0 + i + 3][e] = v.w;
        }
        if (t < TILE_N) {
            if (t < ntile) {
                int id = node_list[i0 + t];
                id_s[t] = id;
                int dg = deg[id];
                bkt_s[t] = (dg < MAXD - 1) ? dg : (MAXD - 1);
            } else { id_s[t] = 0; bkt_s[t] = -1; }
        }
    }
    __syncthreads();

    const int b_first = bkt_s[0];
    const int b_last = bkt_s[ntile - 1];
    const int eg4 = (t >> 4) * 4;
    const int cg4 = (t & 15) * 4;

    for (int b = b_first; b <= b_last; ++b) {
        if (b != b_first) __syncthreads();
        {
            const float4* Wb = (const float4*)(Wt + (size_t)b * KD * IN);
            float4* Wsp = (float4*)Ws;
            #pragma unroll
            for (int q = 0; q < 4; ++q) Wsp[t + q * 256] = Wb[t + q * 256];
        }
        __syncthreads();

        float acc[4][4];
        #pragma unroll
        for (int e2 = 0; e2 < 4; ++e2)
            #pragma unroll
            for (int c = 0; c < 4; ++c) acc[e2][c] = 0.f;

        #pragma unroll 8
        for (int k = 0; k < IN; ++k) {
            const float4 w = *(const float4*)&Ws[k][cg4];
            const float4 m = *(const float4*)&Ms[k][eg4];
            const float me[4] = {m.x, m.y, m.z, m.w};
            #pragma unroll
            for (int e2 = 0; e2 < 4; ++e2) {
                acc[e2][0] += me[e2] * w.x;
                acc[e2][1] += me[e2] * w.y;
                acc[e2][2] += me[e2] * w.z;
                acc[e2][3] += me[e2] * w.w;
            }
        }

        #pragma unroll
        for (int e2 = 0; e2 < 4; ++e2) {
            const int el = eg4 + e2;
            if (el < ntile && bkt_s[el] == b) {
                const size_t o = (size_t)id_s[el] * IN + cg4;
                float4 v = make_float4(acc[e2][0], acc[e2][1], acc[e2][2], acc[e2][3]);
                *(float4*)(y + o) = v;
                float4 sv = make_float4(sigmoidf(v.x), sigmoidf(v.y),
                                        sigmoidf(v.z), sigmoidf(v.w));
                *(float4*)(out + o) = sv;
            }
        }
    }
}

// ---------------- per-timestep: edge-parallel aggregation ----------------
// Wave = 4 independent 16-lane groups; each group walks GEPW consecutive
// dst-sorted edges (lane = 4 channels, float4), accumulating runs of equal
// dst in registers; flush via atomicAdd at run boundaries.

__global__ __launch_bounds__(AGG_BLOCK) void agg3_kernel(
    const float* __restrict__ y, float* __restrict__ out,
    const int* __restrict__ src_csr, const int* __restrict__ dst_csr,
    const int* __restrict__ bkt_csr, const float* __restrict__ ea_csr,
    const float* __restrict__ Wt, int E)
{
    __shared__ float WeL[MAXD][ECH][IN];   // 40 KB
    const int t = threadIdx.x;
    {
        const float4* Wsrc = (const float4*)Wt;
        float4* Wd = (float4*)WeL;
        #pragma unroll
        for (int i = 0; i < MAXD * ECH * IN / 4 / AGG_BLOCK; ++i) {
            int q = t + i * AGG_BLOCK;
            int b = q >> 8;            // /256 float4 per bucket
            int r = q & 255;
            Wd[q] = Wsrc[b * (KD * IN / 4) + (IN * IN / 4) + r];
        }
    }
    __syncthreads();

    const int lane = t & 63;
    const int grp = lane >> 4;        // 0..3
    const int gl = lane & 15;         // 0..15
    const int c0 = gl * 4;            // 4 channels per lane
    const int base = blockIdx.x * AGG_EPB + (t >> 6) * (4 * GEPW) + grp * GEPW;
    const int cnt = min(GEPW, E - base);
    if (cnt <= 0) return;

    // per-lane meta prefetch for this group's GEPW edges
    const int m_idx = base + (gl & (GEPW - 1));
    int s_r = 0, d_r = -1, b_r = 0;
    if (m_idx < E) { s_r = src_csr[m_idx]; d_r = dst_csr[m_idx]; b_r = bkt_csr[m_idx]; }
    const int lane0 = grp * 16;

    int s0 = __shfl(s_r, lane0);
    int cur_d = __shfl(d_r, lane0);
    float4 yv = *(const float4*)(y + (size_t)s0 * IN + c0);
    float4 acc = make_float4(0.f, 0.f, 0.f, 0.f);

    for (int i = 0; i < cnt; ++i) {
        const int b = __shfl(b_r, lane0 + i);
        const int d = __shfl(d_r, lane0 + i);
        // prefetch next edge's y
        float4 yn = make_float4(0.f, 0.f, 0.f, 0.f);
        if (i + 1 < cnt) {
            int sn = __shfl(s_r, lane0 + i + 1);
            yn = *(const float4*)(y + (size_t)sn * IN + c0);
        }
        if (d != cur_d) {
            float* op = out + (size_t)cur_d * IN + c0;
            atomicAdd(op + 0, acc.x); atomicAdd(op + 1, acc.y);
            atomicAdd(op + 2, acc.z); atomicAdd(op + 3, acc.w);
            acc = make_float4(0.f, 0.f, 0.f, 0.f);
            cur_d = d;
        }
        const float4* eap = (const float4*)(ea_csr + (size_t)(base + i) * ECH);
        const float4 e0 = eap[0], e1 = eap[1], e2 = eap[2], e3 = eap[3];
        const float ev[16] = {e0.x, e0.y, e0.z, e0.w, e1.x, e1.y, e1.z, e1.w,
                              e2.x, e2.y, e2.z, e2.w, e3.x, e3.y, e3.z, e3.w};
        float4 z = make_float4(0.f, 0.f, 0.f, 0.f);
        #pragma unroll
        for (int k = 0; k < ECH; ++k) {
            const float4 w = *(const float4*)&WeL[b][k][c0];
            z.x += ev[k] * w.x; z.y += ev[k] * w.y;
            z.z += ev[k] * w.z; z.w += ev[k] * w.w;
        }
        acc.x += sigmoidf(yv.x + z.x);
        acc.y += sigmoidf(yv.y + z.y);
        acc.z += sigmoidf(yv.z + z.z);
        acc.w += sigmoidf(yv.w + z.w);
        yv = yn;
    }
    float* op = out + (size_t)cur_d * IN + c0;
    atomicAdd(op + 0, acc.x); atomicAdd(op + 1, acc.y);
    atomicAdd(op + 2, acc.z); atomicAdd(op + 3, acc.w);
}

// ---------------- readout + pooling ----------------

__global__ __launch_bounds__(256) void readout_kernel(
    const float* __restrict__ x, const float* __restrict__ Wr,
    const int* __restrict__ batch, float* __restrict__ pooled, int N)
{
    __shared__ float Wr_s[TSTEPS][10][IN];
    __shared__ float pool_s[64 * 10];
    const int t = threadIdx.x;
    for (int idx = t; idx < TSTEPS * IN * 10; idx += 256) {
        int tt = idx / (IN * 10);
        int r = idx % (IN * 10);
        int k = r / 10;
        int j = r % 10;
        Wr_s[tt][j][k] = Wr[idx];
    }
    for (int idx = t; idx < 64 * 10; idx += 256) pool_s[idx] = 0.f;
    __syncthreads();

    const int n = blockIdx.x * 256 + t;
    if (n < N) {
        float xr[IN];
        const float4* xp = (const float4*)(x + (size_t)n * IN);
        #pragma unroll
        for (int i = 0; i < IN / 4; ++i) ((float4*)xr)[i] = xp[i];
        float out10[10];
        #pragma unroll
        for (int j = 0; j < 10; ++j) out10[j] = 0.f;
        for (int tt = 0; tt < TSTEPS; ++tt) {
            float lg[10];
            #pragma unroll
            for (int j = 0; j < 10; ++j) {
                const float4* wp = (const float4*)Wr_s[tt][j];
                float s = 0.f;
                #pragma unroll
                for (int i = 0; i < IN / 4; ++i) {
                    float4 w = wp[i];
                    float4 xv = ((const float4*)xr)[i];
                    s += w.x * xv.x + w.y * xv.y + w.z * xv.z + w.w * xv.w;
                }
                lg[j] = s;
            }
            float mx = lg[0];
            #pragma unroll
            for (int j = 1; j < 10; ++j) mx = fmaxf(mx, lg[j]);
            float sum = 0.f;
            #pragma unroll
            for (int j = 0; j < 10; ++j) { lg[j] = __expf(lg[j] - mx); sum += lg[j]; }
            float inv = 1.f / sum;
            #pragma unroll
            for (int j = 0; j < 10; ++j) out10[j] += lg[j] * inv;
        }
        const int g = batch[n];
        #pragma unroll
        for (int j = 0; j < 10; ++j) atomicAdd(&pool_s[g * 10 + j], out10[j]);
    }
    __syncthreads();
    for (int idx = t; idx < 64 * 10; idx += 256) {
        float v = pool_s[idx];
        if (v != 0.f) atomicAdd(&pooled[idx], v);
    }
}

// ---------------- final MLP ----------------

__global__ __launch_bounds__(256) void mlp_kernel(
    const float* __restrict__ pooled,
    const float* __restrict__ fc1w, const float* __restrict__ fc1b,
    const float* __restrict__ fc2w, const float* __restrict__ fc2b,
    const float* __restrict__ fc3w, const float* __restrict__ fc3b,
    float* __restrict__ out, int G)
{
    __shared__ float p_s[64 * 10];
    __shared__ float h1[64 * 128];
    __shared__ float h2[64 * 64];
    const int t = threadIdx.x;
    for (int idx = t; idx < G * 10; idx += 256) p_s[idx] = pooled[idx];
    __syncthreads();
    for (int idx = t; idx < G * 128; idx += 256) {
        int g = idx >> 7, j = idx & 127;
        float s = fc1b[j];
        #pragma unroll
        for (int k = 0; k < 10; ++k) s += p_s[g * 10 + k] * fc1w[k * 128 + j];
        h1[idx] = (s > 0.f) ? s : 0.01f * s;
    }
    __syncthreads();
    for (int idx = t; idx < G * 64; idx += 256) {
        int g = idx >> 6, j = idx & 63;
        float s = fc2b[j];
        for (int k = 0; k < 128; ++k) s += h1[(g << 7) + k] * fc2w[(k << 6) + j];
        h2[idx] = (s > 0.f) ? s : 0.01f * s;
    }
    __syncthreads();
    if (t < G) {
        float s = fc3b[0];
        for (int k = 0; k < 64; ++k) s += h2[(t << 6) + k] * fc3w[k];
        out[t] = (s > 0.f) ? s : 0.01f * s;
    }
}

// ---------------- launch ----------------

extern "C" void kernel_launch(void* const* d_in, const int* in_sizes, int n_in,
                              void* d_out, int out_size, void* d_ws, size_t ws_size,
                              hipStream_t stream)
{
    const float* x     = (const float*)d_in[0];
    const float* ea    = (const float*)d_in[1];
    const float* Wmsg  = (const float*)d_in[2];
    const float* Wread = (const float*)d_in[3];
    const float* fc1w  = (const float*)d_in[4];
    const float* fc1b  = (const float*)d_in[5];
    const float* fc2w  = (const float*)d_in[6];
    const float* fc2b  = (const float*)d_in[7];
    const float* fc3w  = (const float*)d_in[8];
    const float* fc3b  = (const float*)d_in[9];
    const int* ei      = (const int*)d_in[10];
    const int* batch   = (const int*)d_in[11];

    const int N = in_sizes[0] / IN;
    const int E = in_sizes[10] / 2;

    char* ws = (char*)d_ws;
    size_t off = 0;
    auto take = [&](size_t bytes) {
        char* p = ws + off;
        off = (off + bytes + 255) & ~(size_t)255;
        return p;
    };
    // zero-region: [meta | pooled | deg | in_cnt] — single memset per launch
    int* meta      = (int*)take(128);          // [0..9]=nb_cursor
    float* pooled  = (float*)take(64 * 10 * 4);
    int* deg       = (int*)take((size_t)N * 4);
    int* in_cnt    = (int*)take((size_t)N * 4);
    const size_t zero_bytes = (size_t)((char*)in_cnt - (char*)meta) + (size_t)N * 4;
    int* node_list = (int*)take((size_t)N * 4);
    int* cursorN   = (int*)take((size_t)N * 4);
    int* src_csr   = (int*)take((size_t)E * 4);
    int* dst_csr   = (int*)take((size_t)E * 4);
    int* bkt_csr   = (int*)take((size_t)E * 4);
    float* ea_csr  = (float*)take((size_t)E * ECH * 4);
    float* ybuf    = (float*)take((size_t)N * IN * 4);
    float* xbA     = (float*)take((size_t)N * IN * 4);
    float* xbB     = (float*)take((size_t)N * IN * 4);

    int* nb_cursor = meta;

    const int nbN = (N + 255) / 256;
    const int nbE = (E + 255) / 256;

    hipMemsetAsync(meta, 0, zero_bytes, stream);
    hist_kernel<<<nbE, 256, 0, stream>>>(ei, deg, in_cnt, E);
    scan_kernel<<<1, 256, 0, stream>>>(in_cnt, cursorN, deg, nb_cursor, N);
    nb_scatter_kernel<<<nbN, 256, 0, stream>>>(deg, nb_cursor, node_list, N);
    csr_scatter_kernel<<<nbE, 256, 0, stream>>>(ei, ea, deg, cursorN,
                                                src_csr, dst_csr, bkt_csr, ea_csr, E);

    const int nblkY = (N + TILE_N - 1) / TILE_N;
    const int nblkA = (E + AGG_EPB - 1) / AGG_EPB;
    const float* xi = x;
    float* bufs[2] = {xbA, xbB};
    for (int tt = 0; tt < TSTEPS; ++tt) {
        const float* Wt = Wmsg + (size_t)tt * MAXD * KD * IN;
        float* xo = bufs[tt & 1];
        y_kernel<<<nblkY, 256, 0, stream>>>(xi, ybuf, xo, node_list, deg, Wt, N);
        agg3_kernel<<<nblkA, AGG_BLOCK, 0, stream>>>(ybuf, xo, src_csr, dst_csr,
                                                     bkt_csr, ea_csr, Wt, E);
        xi = xo;
    }

    readout_kernel<<<nbN, 256, 0, stream>>>(xi, Wread, batch, pooled, N);
    mlp_kernel<<<1, 256, 0, stream>>>(pooled, fc1w, fc1b, fc2w, fc2b, fc3w, fc3b,
                                      (float*)d_out, out_size);
}